// Round 1
// baseline (245.784 us; speedup 1.0000x reference)
//
#include <hip/hip_runtime.h>
#include <math.h>

// Problem: B=16, N=2049, C=1024, w_qkv is (1024, 3072) row-major.
// out = softmax over n of  scale * (x[b,0,:] @ Wq) . (x[b,n+1,:] @ Wk)
// Reassociated: v[b] = Wk @ (x[b,0,:] @ Wq);  logit[b,n] = scale * x[b,n+1,:].v[b]

#define BATCH 16
#define SEQ   2049
#define CH    1024
#define W3    3072
#define NOUT  2048
#define DSPLIT 4

// ws layout (floats):
//   part  : [0, 4*16*1024)           = 256 KB  (q_cls partials over d-chunks)
//   v     : [65536, 65536+16*1024)   = 64 KB
//   logits: [0, 16*2048)             = 128 KB  (reuses part space after kernel B)

// ---------------- Kernel A: q_cls partials ----------------
// grid (DSPLIT, BATCH), block 256. Each thread: 4 consecutive columns of Wq,
// 256 d-rows. x[b,0,d] staged in LDS (broadcast read).
__global__ __launch_bounds__(256) void qcls_partial_kernel(
    const float* __restrict__ x, const float* __restrict__ w,
    float* __restrict__ part) {
    const int p = blockIdx.x;
    const int b = blockIdx.y;
    const int t = threadIdx.x;
    __shared__ float xs[256];
    const int d0 = p * 256;
    xs[t] = x[(size_t)b * SEQ * CH + d0 + t];
    __syncthreads();
    float4 acc = {0.f, 0.f, 0.f, 0.f};
    const float* wbase = w + (size_t)d0 * W3 + 4 * t;   // Wq = cols [0,1024)
    #pragma unroll 4
    for (int dd = 0; dd < 256; ++dd) {
        float4 wv = *(const float4*)(wbase + (size_t)dd * W3);
        const float xd = xs[dd];
        acc.x += xd * wv.x; acc.y += xd * wv.y;
        acc.z += xd * wv.z; acc.w += xd * wv.w;
    }
    *(float4*)(part + (size_t)(p * BATCH + b) * CH + 4 * t) = acc;
}

// ---------------- Kernel B: v[b,d] = Wk[d,:] . q_cls[b,:] ----------------
// grid 128, block 256 (4 waves). q_cls (sum of 4 partials) staged in 64 KB LDS.
// Each wave handles 2 d-rows; lanes span c (coalesced float4), shuffle-reduce.
__global__ __launch_bounds__(256) void v_kernel(
    const float* __restrict__ w, const float* __restrict__ part,
    float* __restrict__ v) {
    __shared__ float qs[BATCH * CH];   // 64 KB
    const int t = threadIdx.x;
    for (int i = t; i < BATCH * CH; i += 256) {
        qs[i] = part[i] + part[16 * 1024 + i] +
                part[2 * 16 * 1024 + i] + part[3 * 16 * 1024 + i];
    }
    __syncthreads();
    const int lane = t & 63;
    const int wave = t >> 6;
    for (int k = 0; k < 2; ++k) {
        const int d = blockIdx.x * 8 + wave * 2 + k;
        const float* wrow = w + (size_t)d * W3 + CH;    // Wk = cols [1024,2048)
        float4 wv[4];
        #pragma unroll
        for (int j = 0; j < 4; ++j)
            wv[j] = *(const float4*)(wrow + lane * 4 + j * 256);
        #pragma unroll
        for (int b = 0; b < BATCH; ++b) {
            float acc = 0.f;
            #pragma unroll
            for (int j = 0; j < 4; ++j) {
                float4 qv = *(const float4*)(&qs[b * CH + lane * 4 + j * 256]);
                acc += wv[j].x * qv.x + wv[j].y * qv.y
                     + wv[j].z * qv.z + wv[j].w * qv.w;
            }
            #pragma unroll
            for (int off = 32; off > 0; off >>= 1)
                acc += __shfl_down(acc, off, 64);
            if (lane == 0) v[b * CH + d] = acc;
        }
    }
}

// ---------------- Kernel C: logits (the memory-bound streamer) ----------------
// One wave per (b,n) row: 1024-float dot with v[b]. grid 8192 x 256.
__global__ __launch_bounds__(256) void logits_kernel(
    const float* __restrict__ x, const float* __restrict__ v,
    float* __restrict__ logits) {
    const int t = threadIdx.x;
    const int lane = t & 63;
    const int row = blockIdx.x * 4 + (t >> 6);  // 0..32767
    const int b = row >> 11;
    const int n = row & 2047;
    const float* xrow = x + ((size_t)b * SEQ + n + 1) * CH;
    const float* vrow = v + b * CH;
    float acc = 0.f;
    #pragma unroll
    for (int j = 0; j < 4; ++j) {
        float4 xv = *(const float4*)(xrow + lane * 4 + j * 256);
        float4 vv = *(const float4*)(vrow + lane * 4 + j * 256);
        acc += xv.x * vv.x + xv.y * vv.y + xv.z * vv.z + xv.w * vv.w;
    }
    #pragma unroll
    for (int off = 32; off > 0; off >>= 1)
        acc += __shfl_down(acc, off, 64);
    if (lane == 0) logits[row] = acc * 0.03125f;   // scale = C^-0.5 = 1/32
}

// ---------------- Kernel D: softmax over 2048 per batch ----------------
__global__ __launch_bounds__(256) void softmax_kernel(
    const float* __restrict__ logits, float* __restrict__ out) {
    const int b = blockIdx.x;
    const int t = threadIdx.x;
    __shared__ float sm[256];
    float val[8];
    float m = -1e30f;
    #pragma unroll
    for (int i = 0; i < 8; ++i) {
        val[i] = logits[b * NOUT + t + i * 256];
        m = fmaxf(m, val[i]);
    }
    sm[t] = m; __syncthreads();
    for (int s = 128; s > 0; s >>= 1) {
        if (t < s) sm[t] = fmaxf(sm[t], sm[t + s]);
        __syncthreads();
    }
    const float mx = sm[0];
    __syncthreads();
    float e[8];
    float sum = 0.f;
    #pragma unroll
    for (int i = 0; i < 8; ++i) { e[i] = expf(val[i] - mx); sum += e[i]; }
    sm[t] = sum; __syncthreads();
    for (int s = 128; s > 0; s >>= 1) {
        if (t < s) sm[t] += sm[t + s];
        __syncthreads();
    }
    const float inv = 1.0f / sm[0];
    #pragma unroll
    for (int i = 0; i < 8; ++i) out[b * NOUT + t + i * 256] = e[i] * inv;
}

extern "C" void kernel_launch(void* const* d_in, const int* in_sizes, int n_in,
                              void* d_out, int out_size, void* d_ws, size_t ws_size,
                              hipStream_t stream) {
    const float* x = (const float*)d_in[0];   // (16, 2049, 1024) fp32
    const float* w = (const float*)d_in[1];   // (1024, 3072) fp32
    float* out = (float*)d_out;               // (16, 2048) fp32
    float* ws = (float*)d_ws;

    float* part   = ws;            // 65536 floats (256 KB)
    float* vbuf   = ws + 65536;    // 16384 floats (64 KB)
    float* logits = ws;            // 32768 floats (reuses part space; B is done before C)

    qcls_partial_kernel<<<dim3(DSPLIT, BATCH), 256, 0, stream>>>(x, w, part);
    v_kernel<<<128, 256, 0, stream>>>(w, part, vbuf);
    logits_kernel<<<8192, 256, 0, stream>>>(x, vbuf, logits);
    softmax_kernel<<<BATCH, 256, 0, stream>>>(logits, out);
}

// Round 2
// 220.324 us; speedup vs baseline: 1.1156x; 1.1156x over previous
//
#include <hip/hip_runtime.h>
#include <math.h>

// Problem: B=16, N=2049, C=1024, w_qkv is (1024, 3072) row-major.
// out = softmax over n of  scale * (x[b,0,:] @ Wq) . (x[b,n+1,:] @ Wk)
// Reassociated: q_cls[b] = Wq^T x[b,0,:];  v[b] = Wk @ q_cls[b];
//               logit[b,n] = scale * x[b,n+1,:] . v[b]
// Dominant cost: streaming x once (134 MB) in the logits kernel -> HBM roofline ~21 us.

#define BATCH 16
#define SEQ   2049
#define CH    1024
#define W3    3072
#define NOUT  2048

// ws layout (floats):
//   part   : [0, 64*16*1024)        = 4 MB   (q_cls partials over 64 d-chunks)
//   qcls   : [1048576, +16384)      = 64 KB
//   v      : [1064960, +16384)      = 64 KB
//   logits : [1081344, +32768)      = 128 KB

// ---------------- Kernel A: q_cls partials ----------------
// grid (4 colchunks, 64 dchunks), block = 64 (one wave).
// Each wave: disjoint Wq tile [d0:d0+16) x [c0:c0+256), float4-coalesced rows
// (64 lanes x 16 B = 1 KB/row). x_cls tile for ALL 16 batches staged in LDS
// (broadcast reads, conflict-free). Wq read exactly once chip-wide (4 MB).
__global__ __launch_bounds__(64) void qcls_partial_kernel(
    const float* __restrict__ x, const float* __restrict__ w,
    float* __restrict__ part) {
    const int ci = blockIdx.x;          // col chunk: 256 cols
    const int pi = blockIdx.y;          // d chunk: 16 rows
    const int lane = threadIdx.x;
    const int d0 = pi * 16;
    __shared__ float xs[BATCH * 16];    // xs[b*16 + dd] = x[b,0,d0+dd]
    #pragma unroll
    for (int i = lane; i < BATCH * 16; i += 64) {
        const int b = i >> 4, dd = i & 15;
        xs[i] = x[(size_t)b * SEQ * CH + d0 + dd];
    }
    __syncthreads();
    const int c = ci * 256 + lane * 4;
    float4 acc[BATCH];
    #pragma unroll
    for (int b = 0; b < BATCH; ++b) acc[b] = {0.f, 0.f, 0.f, 0.f};
    #pragma unroll 4
    for (int dd = 0; dd < 16; ++dd) {
        const float4 wv = *(const float4*)(w + (size_t)(d0 + dd) * W3 + c);
        #pragma unroll
        for (int b = 0; b < BATCH; ++b) {
            const float s = xs[b * 16 + dd];
            acc[b].x += s * wv.x; acc[b].y += s * wv.y;
            acc[b].z += s * wv.z; acc[b].w += s * wv.w;
        }
    }
    #pragma unroll
    for (int b = 0; b < BATCH; ++b)
        *(float4*)(part + (size_t)pi * BATCH * CH + b * CH + c) = acc[b];
}

// ---------------- Kernel A2: reduce 64 partials -> q_cls ----------------
// grid 64, block 256. Thread owns one (b,c); coalesced across c.
__global__ __launch_bounds__(256) void qcls_reduce_kernel(
    const float* __restrict__ part, float* __restrict__ qcls) {
    const int id = blockIdx.x * 256 + threadIdx.x;   // b*1024 + c
    float s = 0.f;
    #pragma unroll 8
    for (int p = 0; p < 64; ++p) s += part[(size_t)p * BATCH * CH + id];
    qcls[id] = s;
}

// ---------------- Kernel B: v[b,d] = Wk[d,:] . q_cls[b,:] ----------------
// grid 128, block 256 (4 waves). q_cls (64 KB) staged in LDS.
// Each wave handles 2 d-rows; lanes span c (coalesced float4), shuffle-reduce.
__global__ __launch_bounds__(256) void v_kernel(
    const float* __restrict__ w, const float* __restrict__ qcls,
    float* __restrict__ v) {
    __shared__ float qs[BATCH * CH];   // 64 KB
    const int t = threadIdx.x;
    for (int i = t; i < BATCH * CH; i += 256) qs[i] = qcls[i];
    __syncthreads();
    const int lane = t & 63;
    const int wave = t >> 6;
    #pragma unroll
    for (int k = 0; k < 2; ++k) {
        const int d = blockIdx.x * 8 + wave * 2 + k;
        const float* wrow = w + (size_t)d * W3 + CH;    // Wk = cols [1024,2048)
        float4 wv[4];
        #pragma unroll
        for (int j = 0; j < 4; ++j)
            wv[j] = *(const float4*)(wrow + lane * 4 + j * 256);
        #pragma unroll
        for (int b = 0; b < BATCH; ++b) {
            float acc = 0.f;
            #pragma unroll
            for (int j = 0; j < 4; ++j) {
                float4 qv = *(const float4*)(&qs[b * CH + lane * 4 + j * 256]);
                acc += wv[j].x * qv.x + wv[j].y * qv.y
                     + wv[j].z * qv.z + wv[j].w * qv.w;
            }
            #pragma unroll
            for (int off = 32; off > 0; off >>= 1)
                acc += __shfl_down(acc, off, 64);
            if (lane == 0) v[b * CH + d] = acc;
        }
    }
}

// ---------------- Kernel C: logits (the memory-bound streamer) ----------------
// One wave per (b,n) row: 1024-float dot with v[b]. grid 8192 x 256.
__global__ __launch_bounds__(256) void logits_kernel(
    const float* __restrict__ x, const float* __restrict__ v,
    float* __restrict__ logits) {
    const int t = threadIdx.x;
    const int lane = t & 63;
    const int row = blockIdx.x * 4 + (t >> 6);  // 0..32767
    const int b = row >> 11;
    const int n = row & 2047;
    const float* xrow = x + ((size_t)b * SEQ + n + 1) * CH;
    const float* vrow = v + b * CH;
    float acc = 0.f;
    #pragma unroll
    for (int j = 0; j < 4; ++j) {
        float4 xv = *(const float4*)(xrow + lane * 4 + j * 256);
        float4 vv = *(const float4*)(vrow + lane * 4 + j * 256);
        acc += xv.x * vv.x + xv.y * vv.y + xv.z * vv.z + xv.w * vv.w;
    }
    #pragma unroll
    for (int off = 32; off > 0; off >>= 1)
        acc += __shfl_down(acc, off, 64);
    if (lane == 0) logits[row] = acc * 0.03125f;   // scale = C^-0.5 = 1/32
}

// ---------------- Kernel D: softmax over 2048 per batch ----------------
__global__ __launch_bounds__(256) void softmax_kernel(
    const float* __restrict__ logits, float* __restrict__ out) {
    const int b = blockIdx.x;
    const int t = threadIdx.x;
    __shared__ float sm[256];
    float val[8];
    float m = -1e30f;
    #pragma unroll
    for (int i = 0; i < 8; ++i) {
        val[i] = logits[b * NOUT + t + i * 256];
        m = fmaxf(m, val[i]);
    }
    sm[t] = m; __syncthreads();
    for (int s = 128; s > 0; s >>= 1) {
        if (t < s) sm[t] = fmaxf(sm[t], sm[t + s]);
        __syncthreads();
    }
    const float mx = sm[0];
    __syncthreads();
    float e[8];
    float sum = 0.f;
    #pragma unroll
    for (int i = 0; i < 8; ++i) { e[i] = expf(val[i] - mx); sum += e[i]; }
    sm[t] = sum; __syncthreads();
    for (int s = 128; s > 0; s >>= 1) {
        if (t < s) sm[t] += sm[t + s];
        __syncthreads();
    }
    const float inv = 1.0f / sm[0];
    #pragma unroll
    for (int i = 0; i < 8; ++i) out[b * NOUT + t + i * 256] = e[i] * inv;
}

extern "C" void kernel_launch(void* const* d_in, const int* in_sizes, int n_in,
                              void* d_out, int out_size, void* d_ws, size_t ws_size,
                              hipStream_t stream) {
    const float* x = (const float*)d_in[0];   // (16, 2049, 1024) fp32
    const float* w = (const float*)d_in[1];   // (1024, 3072) fp32
    float* out = (float*)d_out;               // (16, 2048) fp32
    float* ws = (float*)d_ws;

    float* part   = ws;                       // 1,048,576 floats (4 MB)
    float* qcls   = ws + 1048576;             // 16384 floats
    float* vbuf   = ws + 1048576 + 16384;     // 16384 floats
    float* logits = ws + 1048576 + 32768;     // 32768 floats

    qcls_partial_kernel<<<dim3(4, 64), 64, 0, stream>>>(x, w, part);
    qcls_reduce_kernel<<<64, 256, 0, stream>>>(part, qcls);
    v_kernel<<<128, 256, 0, stream>>>(w, qcls, vbuf);
    logits_kernel<<<8192, 256, 0, stream>>>(x, vbuf, logits);
    softmax_kernel<<<BATCH, 256, 0, stream>>>(logits, out);
}